// Round 8
// baseline (181.496 us; speedup 1.0000x reference)
//
#include <hip/hip_runtime.h>
#include <stdint.h>
#include <stddef.h>

#define Bb 8
#define Cc 128
#define Hh 96
#define Ww 160
#define HW (Hh*Ww)         // 15360
#define Kk 81

typedef __attribute__((ext_vector_type(8))) short short8;
typedef __attribute__((ext_vector_type(4))) float floatx4;
typedef __attribute__((ext_vector_type(4))) unsigned int uintx4;

__device__ __forceinline__ uint32_t bf16rne(float f) {
  uint32_t u = __float_as_uint(f);
  return (u + 0x7FFFu + ((u >> 16) & 1u)) >> 16;
}

#define SBAR() __builtin_amdgcn_sched_barrier(0)

// ---------------------------------------------------------------------------
// R14: transpose invariant at ~3.3 TB/s across FIVE schedules (R9-R13:
// 54-58.5us; segments 128B->1024B, occupancy 16-66%, conflicts 0-3.9M,
// VGPR 12-88). The one untried mechanism: global_load_lds (direct TA->LDS,
// no VGPR return path). Every prior version had its loads serialized by
// register reuse (VGPR_Count=16); global_load_lds issues ALL 16KB of a
// block's reads instantly -> 8 blocks/CU = ~128KB in flight per CU, the
// max this structure can express. If this doesn't move the wall, 3.3 TB/s
// is this op's measured ceiling and the transpose is at roofline.
// Bytes + rounding identical -> bit-identical. corr_t3/fallback unchanged.
// ---------------------------------------------------------------------------

// ---- transpose+convert: (B,C,H,W) f32 -> (B, C/8, HW, 8) bf16 -------------
#define TPX3 512
typedef const __attribute__((address_space(1))) void* gas_t;
typedef __attribute__((address_space(3))) void* las_t;

__global__ __launch_bounds__(256, 8)
void transpose_kernel(const float* __restrict__ x1, const float* __restrict__ x2,
                      ushort* __restrict__ x1t, ushort* __restrict__ x2t) {
  __shared__ float lds[8][TPX3];        // 16384 B, rows linear (gload_lds dest)
  const int t   = threadIdx.x;
  const int b   = blockIdx.y;
  const int px0 = blockIdx.x * TPX3;
  const int zz  = blockIdx.z;           // 0..31 = tensor*16 + cg
  const int cg  = zz & 15;
  const float* src = (zz >> 4) ? x2 : x1;
  ushort*      dst = (zz >> 4) ? x2t : x1t;

  // ---- phase 1: 16 global_load_lds dwordx4 (4 per wave), zero VGPR staging.
  // instr (r, q): lane l loads 16B from src[ch(r)][px0 + q*256 + l*4 ..]
  // into lds[r][q*256 + l*4 ..]  (dest base wave-uniform, lane*16 linear).
  const int wv   = t >> 6;
  const int lane = t & 63;
  const float* gbase = src + (size_t)(b * Cc + cg * 8) * HW + px0 + lane * 4;
#pragma unroll
  for (int i = 0; i < 2; ++i) {
#pragma unroll
    for (int q = 0; q < 2; ++q) {
      const int r = wv * 2 + i;
      const float* gp = gbase + (size_t)r * HW + q * 256;
      __builtin_amdgcn_global_load_lds((gas_t)gp, (las_t)&lds[r][q * 256],
                                       16, 0, 0);
    }
  }

  __syncthreads();   // compiler emits s_waitcnt vmcnt(0) before s_barrier

  // ---- phase 2: 2 px/thread; pack 8ch bf16; 1024B contiguous wave-stores.
  // Each ds_read instr: all lanes read one ROW (64 consecutive f32) -> free.
  ushort* dbase = dst + (((size_t)b * 16 + cg) * HW + px0) * 8;
#pragma unroll
  for (int j = 0; j < 2; ++j) {
    const int px = j * 256 + t;
    float c0 = lds[0][px], c1 = lds[1][px], c2 = lds[2][px], c3 = lds[3][px];
    float c4 = lds[4][px], c5 = lds[5][px], c6 = lds[6][px], c7 = lds[7][px];
    uintx4 q = (uintx4){bf16rne(c0) | (bf16rne(c1) << 16),
                        bf16rne(c2) | (bf16rne(c3) << 16),
                        bf16rne(c4) | (bf16rne(c5) << 16),
                        bf16rne(c6) | (bf16rne(c7) << 16)};
    *(uintx4*)&dbase[(size_t)px * 8] = q;
  }
}

// ---- correlation on (B, C/8, HW, 8) bf16 (unchanged from R13) -------------
__device__ __forceinline__ int clampi(int v, int lo, int hi) {
  return v < lo ? lo : (v > hi ? hi : v);
}

#define CKSTEP ((long)4 * HW * 8)

#define LOADRAW(dst, tt, ckc)                                                  \
  dst = *(const short8*)&base2c[rowoff##tt + (ckc) * CKSTEP];

#define ZSEL(v, tt)                                                            \
  v = (okw && (unsigned)(gh2b + (tt)) < (unsigned)Hh) ? v                      \
      : (short8){0, 0, 0, 0, 0, 0, 0, 0};

__global__ __launch_bounds__(256, 3)
void corr_t3_kernel(const ushort* __restrict__ x1t, const ushort* __restrict__ x2t,
                    float* __restrict__ out) {
  __shared__ float ldsOut[Kk * 66];   // 21384 B, stride-66 pad (bank spread)

  const int tid  = threadIdx.x;
  const int flat = blockIdx.x;
  const int b  = flat & 7;
  const int j  = flat >> 3;        // 0..239
  const int by = j / 10;           // 0..23
  const int bx = j - by * 10;      // 0..9
  const int w0 = bx * 16;
  const int h0 = by * 4;

  const int lane = tid & 63;
  const int wv   = tid >> 6;       // 0..3
  const int vy = wv & 1, vx = wv >> 1;
  const int n = lane & 15, quad = lane >> 4;
  const int s = n >> 3, pw = n & 7;

  floatx4 acc[10];
#pragma unroll
  for (int t = 0; t < 10; ++t) acc[t] = (floatx4){0.f, 0.f, 0.f, 0.f};

  const int gw2  = w0 - 4 + 8 * vx + n;
  const bool okw = (unsigned)gw2 < (unsigned)Ww;
  const int gw2c = clampi(gw2, 0, Ww - 1);
  const int gh2b = h0 - 4 + 2 * vy;

  const ushort* base2c = x2t + (((long)b * 16 + quad) * HW + gw2c) * 8;
  const ushort* base1  = x1t + (((long)b * 16 + quad) * HW
                                + (long)(h0 + 2 * vy + s) * Ww
                                + (w0 + 8 * vx + pw)) * 8;

  const long rowoff0 = (long)clampi(gh2b + 0, 0, Hh - 1) * (Ww * 8);
  const long rowoff1 = (long)clampi(gh2b + 1, 0, Hh - 1) * (Ww * 8);
  const long rowoff2 = (long)clampi(gh2b + 2, 0, Hh - 1) * (Ww * 8);
  const long rowoff3 = (long)clampi(gh2b + 3, 0, Hh - 1) * (Ww * 8);
  const long rowoff4 = (long)clampi(gh2b + 4, 0, Hh - 1) * (Ww * 8);
  const long rowoff5 = (long)clampi(gh2b + 5, 0, Hh - 1) * (Ww * 8);
  const long rowoff6 = (long)clampi(gh2b + 6, 0, Hh - 1) * (Ww * 8);
  const long rowoff7 = (long)clampi(gh2b + 7, 0, Hh - 1) * (Ww * 8);
  const long rowoff8 = (long)clampi(gh2b + 8, 0, Hh - 1) * (Ww * 8);
  const long rowoff9 = (long)clampi(gh2b + 9, 0, Hh - 1) * (Ww * 8);

  const short8 bf0 = *(const short8*)&base1[0 * CKSTEP];
  const short8 bf1 = *(const short8*)&base1[1 * CKSTEP];
  const short8 bf2 = *(const short8*)&base1[2 * CKSTEP];
  const short8 bf3 = *(const short8*)&base1[3 * CKSTEP];

  short8 aA0, aA1, aA2, aA3, aA4, aA5, aA6, aA7, aA8, aA9;
  short8 aB0, aB1, aB2, aB3, aB4, aB5, aB6, aB7, aB8, aB9;

  LOADRAW(aA0, 0, 0); LOADRAW(aA1, 1, 0); LOADRAW(aA2, 2, 0); LOADRAW(aA3, 3, 0);
  LOADRAW(aA4, 4, 0); LOADRAW(aA5, 5, 0); LOADRAW(aA6, 6, 0); LOADRAW(aA7, 7, 0);
  LOADRAW(aA8, 8, 0); LOADRAW(aA9, 9, 0);
  SBAR();
  LOADRAW(aB0, 0, 1); LOADRAW(aB1, 1, 1); LOADRAW(aB2, 2, 1); LOADRAW(aB3, 3, 1);
  LOADRAW(aB4, 4, 1); LOADRAW(aB5, 5, 1); LOADRAW(aB6, 6, 1); LOADRAW(aB7, 7, 1);
  LOADRAW(aB8, 8, 1); LOADRAW(aB9, 9, 1);
  SBAR();
  ZSEL(aA0, 0); ZSEL(aA1, 1); ZSEL(aA2, 2); ZSEL(aA3, 3); ZSEL(aA4, 4);
  ZSEL(aA5, 5); ZSEL(aA6, 6); ZSEL(aA7, 7); ZSEL(aA8, 8); ZSEL(aA9, 9);
  acc[0] = __builtin_amdgcn_mfma_f32_16x16x32_bf16(aA0, bf0, acc[0], 0, 0, 0);
  acc[1] = __builtin_amdgcn_mfma_f32_16x16x32_bf16(aA1, bf0, acc[1], 0, 0, 0);
  acc[2] = __builtin_amdgcn_mfma_f32_16x16x32_bf16(aA2, bf0, acc[2], 0, 0, 0);
  acc[3] = __builtin_amdgcn_mfma_f32_16x16x32_bf16(aA3, bf0, acc[3], 0, 0, 0);
  acc[4] = __builtin_amdgcn_mfma_f32_16x16x32_bf16(aA4, bf0, acc[4], 0, 0, 0);
  acc[5] = __builtin_amdgcn_mfma_f32_16x16x32_bf16(aA5, bf0, acc[5], 0, 0, 0);
  acc[6] = __builtin_amdgcn_mfma_f32_16x16x32_bf16(aA6, bf0, acc[6], 0, 0, 0);
  acc[7] = __builtin_amdgcn_mfma_f32_16x16x32_bf16(aA7, bf0, acc[7], 0, 0, 0);
  acc[8] = __builtin_amdgcn_mfma_f32_16x16x32_bf16(aA8, bf0, acc[8], 0, 0, 0);
  acc[9] = __builtin_amdgcn_mfma_f32_16x16x32_bf16(aA9, bf0, acc[9], 0, 0, 0);
  SBAR();
  LOADRAW(aA0, 0, 2); LOADRAW(aA1, 1, 2); LOADRAW(aA2, 2, 2); LOADRAW(aA3, 3, 2);
  LOADRAW(aA4, 4, 2); LOADRAW(aA5, 5, 2); LOADRAW(aA6, 6, 2); LOADRAW(aA7, 7, 2);
  LOADRAW(aA8, 8, 2); LOADRAW(aA9, 9, 2);
  SBAR();
  ZSEL(aB0, 0); ZSEL(aB1, 1); ZSEL(aB2, 2); ZSEL(aB3, 3); ZSEL(aB4, 4);
  ZSEL(aB5, 5); ZSEL(aB6, 6); ZSEL(aB7, 7); ZSEL(aB8, 8); ZSEL(aB9, 9);
  acc[0] = __builtin_amdgcn_mfma_f32_16x16x32_bf16(aB0, bf1, acc[0], 0, 0, 0);
  acc[1] = __builtin_amdgcn_mfma_f32_16x16x32_bf16(aB1, bf1, acc[1], 0, 0, 0);
  acc[2] = __builtin_amdgcn_mfma_f32_16x16x32_bf16(aB2, bf1, acc[2], 0, 0, 0);
  acc[3] = __builtin_amdgcn_mfma_f32_16x16x32_bf16(aB3, bf1, acc[3], 0, 0, 0);
  acc[4] = __builtin_amdgcn_mfma_f32_16x16x32_bf16(aB4, bf1, acc[4], 0, 0, 0);
  acc[5] = __builtin_amdgcn_mfma_f32_16x16x32_bf16(aB5, bf1, acc[5], 0, 0, 0);
  acc[6] = __builtin_amdgcn_mfma_f32_16x16x32_bf16(aB6, bf1, acc[6], 0, 0, 0);
  acc[7] = __builtin_amdgcn_mfma_f32_16x16x32_bf16(aB7, bf1, acc[7], 0, 0, 0);
  acc[8] = __builtin_amdgcn_mfma_f32_16x16x32_bf16(aB8, bf1, acc[8], 0, 0, 0);
  acc[9] = __builtin_amdgcn_mfma_f32_16x16x32_bf16(aB9, bf1, acc[9], 0, 0, 0);
  SBAR();
  LOADRAW(aB0, 0, 3); LOADRAW(aB1, 1, 3); LOADRAW(aB2, 2, 3); LOADRAW(aB3, 3, 3);
  LOADRAW(aB4, 4, 3); LOADRAW(aB5, 5, 3); LOADRAW(aB6, 6, 3); LOADRAW(aB7, 7, 3);
  LOADRAW(aB8, 8, 3); LOADRAW(aB9, 9, 3);
  SBAR();
  ZSEL(aA0, 0); ZSEL(aA1, 1); ZSEL(aA2, 2); ZSEL(aA3, 3); ZSEL(aA4, 4);
  ZSEL(aA5, 5); ZSEL(aA6, 6); ZSEL(aA7, 7); ZSEL(aA8, 8); ZSEL(aA9, 9);
  acc[0] = __builtin_amdgcn_mfma_f32_16x16x32_bf16(aA0, bf2, acc[0], 0, 0, 0);
  acc[1] = __builtin_amdgcn_mfma_f32_16x16x32_bf16(aA1, bf2, acc[1], 0, 0, 0);
  acc[2] = __builtin_amdgcn_mfma_f32_16x16x32_bf16(aA2, bf2, acc[2], 0, 0, 0);
  acc[3] = __builtin_amdgcn_mfma_f32_16x16x32_bf16(aA3, bf2, acc[3], 0, 0, 0);
  acc[4] = __builtin_amdgcn_mfma_f32_16x16x32_bf16(aA4, bf2, acc[4], 0, 0, 0);
  acc[5] = __builtin_amdgcn_mfma_f32_16x16x32_bf16(aA5, bf2, acc[5], 0, 0, 0);
  acc[6] = __builtin_amdgcn_mfma_f32_16x16x32_bf16(aA6, bf2, acc[6], 0, 0, 0);
  acc[7] = __builtin_amdgcn_mfma_f32_16x16x32_bf16(aA7, bf2, acc[7], 0, 0, 0);
  acc[8] = __builtin_amdgcn_mfma_f32_16x16x32_bf16(aA8, bf2, acc[8], 0, 0, 0);
  acc[9] = __builtin_amdgcn_mfma_f32_16x16x32_bf16(aA9, bf2, acc[9], 0, 0, 0);
  SBAR();
  ZSEL(aB0, 0); ZSEL(aB1, 1); ZSEL(aB2, 2); ZSEL(aB3, 3); ZSEL(aB4, 4);
  ZSEL(aB5, 5); ZSEL(aB6, 6); ZSEL(aB7, 7); ZSEL(aB8, 8); ZSEL(aB9, 9);
  acc[0] = __builtin_amdgcn_mfma_f32_16x16x32_bf16(aB0, bf3, acc[0], 0, 0, 0);
  acc[1] = __builtin_amdgcn_mfma_f32_16x16x32_bf16(aB1, bf3, acc[1], 0, 0, 0);
  acc[2] = __builtin_amdgcn_mfma_f32_16x16x32_bf16(aB2, bf3, acc[2], 0, 0, 0);
  acc[3] = __builtin_amdgcn_mfma_f32_16x16x32_bf16(aB3, bf3, acc[3], 0, 0, 0);
  acc[4] = __builtin_amdgcn_mfma_f32_16x16x32_bf16(aB4, bf3, acc[4], 0, 0, 0);
  acc[5] = __builtin_amdgcn_mfma_f32_16x16x32_bf16(aB5, bf3, acc[5], 0, 0, 0);
  acc[6] = __builtin_amdgcn_mfma_f32_16x16x32_bf16(aB6, bf3, acc[6], 0, 0, 0);
  acc[7] = __builtin_amdgcn_mfma_f32_16x16x32_bf16(aB7, bf3, acc[7], 0, 0, 0);
  acc[8] = __builtin_amdgcn_mfma_f32_16x16x32_bf16(aB8, bf3, acc[8], 0, 0, 0);
  acc[9] = __builtin_amdgcn_mfma_f32_16x16x32_bf16(aB9, bf3, acc[9], 0, 0, 0);

  // ---- epilogue: scatter to padded LDS, then coalesced full-line writes ----
  const float scale = 1.0f / 128.0f;
  const int prow = 2 * vy + s;           // 0..3 within tile
  const int pcol = 8 * vx + pw;          // 0..15 within tile
#pragma unroll
  for (int t = 0; t < 10; ++t) {
    int di = t - 4 - s;
    if ((unsigned)(di + 4) > 8u) continue;
#pragma unroll
    for (int r = 0; r < 4; ++r) {
      int dj = quad * 4 + r - 4 - pw;
      if ((unsigned)(dj + 4) > 8u) continue;
      int kk = (di + 4) * 9 + (dj + 4);
      ldsOut[kk * 66 + prow * 16 + pcol] = acc[t][r] * scale;
    }
  }
  __syncthreads();

  for (int idx = tid; idx < Kk * 64; idx += 256) {
    int kk  = idx >> 6;
    int rem = idx & 63;                  // hh*16 + ww
    int hh  = rem >> 4;
    int ww  = rem & 15;
    out[((size_t)b * Kk + kk) * HW + (size_t)(h0 + hh) * Ww + (w0 + ww)] =
        ldsOut[kk * 66 + rem];
  }
}

// ---------------------------------------------------------------------------
// R6 kernel kept verbatim as fallback when workspace is too small.
// ---------------------------------------------------------------------------
__global__ __launch_bounds__(512, 4)
void corr_kernel(const float* __restrict__ x1, const float* __restrict__ x2,
                 float* __restrict__ out) {
  __shared__ __align__(16) ushort ldsX2[16*24*40];
  __shared__ __align__(16) ushort ldsX1[8*16*40];

  const int tid = threadIdx.x;
  const int flat = blockIdx.x;
  const int b  = flat & 7;
  const int j  = flat >> 3;
  const int by = j / 10;
  const int bx = j - by * 10;
  const int w0 = bx * 16;
  const int h0 = by * 8;

  const int lane = tid & 63;
  const int wv   = tid >> 6;
  const int vy = wv & 3, vx = wv >> 2;
  const int n = lane & 15, quad = lane >> 4;
  const int s = n >> 3, pw = n & 7;

  floatx4 acc[10];
#pragma unroll
  for (int t = 0; t < 10; ++t) acc[t] = (floatx4){0.f, 0.f, 0.f, 0.f};

  for (int ck = 0; ck < 4; ++ck) {
    const int c0 = ck * 32;
    if (ck) __syncthreads();

#pragma unroll
    for (int it = 0; it < 3; ++it) {
      int T   = it * 512 + tid;
      int w24 = T % 24;
      int t2  = T / 24;
      int rw  = t2 & 15;
      int cg  = t2 >> 4;
      int gh = h0 - 4 + rw;
      int gw = w0 - 4 + w24;
      bool ok = ((unsigned)gh < Hh) && ((unsigned)gw < Ww);
      const float* src = x2 + ((size_t)(b*Cc + c0 + cg*8) * HW + gh*Ww + gw);
      uint32_t p0, p1, p2, p3;
      {
        float a0 = ok ? src[0*HW] : 0.f;
        float a1 = ok ? src[1*HW] : 0.f;
        float a2 = ok ? src[2*HW] : 0.f;
        float a3 = ok ? src[3*HW] : 0.f;
        float a4 = ok ? src[4*HW] : 0.f;
        float a5 = ok ? src[5*HW] : 0.f;
        float a6 = ok ? src[6*HW] : 0.f;
        float a7 = ok ? src[7*HW] : 0.f;
        p0 = bf16rne(a0) | (bf16rne(a1) << 16);
        p1 = bf16rne(a2) | (bf16rne(a3) << 16);
        p2 = bf16rne(a4) | (bf16rne(a5) << 16);
        p3 = bf16rne(a6) | (bf16rne(a7) << 16);
      }
      *(uintx4*)&ldsX2[(rw*24 + w24)*40 + cg*8] = (uintx4){p0, p1, p2, p3};
    }

    {
      int T  = tid;
      int wl = T & 15;
      int t2 = T >> 4;
      int rl = t2 & 7;
      int cg = t2 >> 3;
      const float* src = x1 + ((size_t)(b*Cc + c0 + cg*8) * HW
                               + (h0 + rl)*Ww + (w0 + wl));
      uint32_t p0, p1, p2, p3;
      float a0 = src[0*HW], a1 = src[1*HW], a2 = src[2*HW], a3 = src[3*HW];
      float a4 = src[4*HW], a5 = src[5*HW], a6 = src[6*HW], a7 = src[7*HW];
      p0 = bf16rne(a0) | (bf16rne(a1) << 16);
      p1 = bf16rne(a2) | (bf16rne(a3) << 16);
      p2 = bf16rne(a4) | (bf16rne(a5) << 16);
      p3 = bf16rne(a6) | (bf16rne(a7) << 16);
      *(uintx4*)&ldsX1[(rl*16 + wl)*40 + cg*8] = (uintx4){p0, p1, p2, p3};
    }

    __syncthreads();

    short8 bfrag = *(const short8*)&ldsX1[((2*vy + s)*16 + 8*vx + pw)*40 + quad*8];
#pragma unroll
    for (int t = 0; t < 10; ++t) {
      short8 afrag = *(const short8*)&ldsX2[((2*vy + t)*24 + 8*vx + n)*40 + quad*8];
      acc[t] = __builtin_amdgcn_mfma_f32_16x16x32_bf16(afrag, bfrag, acc[t], 0, 0, 0);
    }
  }

  const float scale = 1.0f / 128.0f;
  const int ph  = h0 + 2*vy + s;
  const int pwg = w0 + 8*vx + pw;
#pragma unroll
  for (int t = 0; t < 10; ++t) {
    int di = t - 4 - s;
    if ((unsigned)(di + 4) > 8u) continue;
#pragma unroll
    for (int r = 0; r < 4; ++r) {
      int dj = quad*4 + r - 4 - pw;
      if ((unsigned)(dj + 4) > 8u) continue;
      int kk = (di + 4) * 9 + (dj + 4);
      out[((size_t)b*Kk + kk) * HW + ph*Ww + pwg] = acc[t][r] * scale;
    }
  }
}

extern "C" void kernel_launch(void* const* d_in, const int* in_sizes, int n_in,
                              void* d_out, int out_size, void* d_ws, size_t ws_size,
                              hipStream_t stream) {
  const float* x1 = (const float*)d_in[0];
  const float* x2 = (const float*)d_in[1];
  float* out = (float*)d_out;

  const size_t elems = (size_t)Bb * HW * Cc;              // 15,728,640
  const size_t need  = 2 * elems * sizeof(ushort);        // 62,914,560 B

  if (d_ws != nullptr && ws_size >= need) {
    ushort* x1t = (ushort*)d_ws;
    ushort* x2t = x1t + elems;
    transpose_kernel<<<dim3(HW / TPX3, Bb, 32), dim3(256, 1, 1), 0, stream>>>(
        x1, x2, x1t, x2t);
    corr_t3_kernel<<<dim3(1920, 1, 1), dim3(256, 1, 1), 0, stream>>>(x1t, x2t, out);
  } else {
    corr_kernel<<<dim3(960, 1, 1), dim3(512, 1, 1), 0, stream>>>(x1, x2, out);
  }
}